// Round 3
// baseline (948.327 us; speedup 1.0000x reference)
//
#include <hip/hip_runtime.h>
#include <math.h>
#include <cstddef>

#define T_SAMP 256000
#define TFRM   4001
#define NF     257
#define NB     40
#define NBATCH 32
#define OFFOUT ((size_t)NBATCH*NB*TFRM)
#define TWO_PI 6.283185307179586f

typedef _Float16 f16;

#define MV_ELEMS  ((size_t)NBATCH * TFRM * NF)            // 32,904,224 halfs
#define MV_BYTES  (MV_ELEMS * 2)                          // 65,808,448
#define PF_BYTES  ((size_t)16384)
#define IN_PLACE_NEED (MV_BYTES + PF_BYTES)               // 65,824,832 (< proven 66,334,784)
#define TWO_BUF_NEED  (2*MV_BYTES + PF_BYTES)             // 131,633,280

// K2 chunking
#define CHUNKS 16
#define CT     251            // ceil(4001/16)
#define WARM   288            // 0.9526^288 ~ 9e-7 (< fp16 noise)
#define NCHAN  (NBATCH * NF)  // 8224
#define K2_THREADS (CHUNKS * NCHAN)   // 131,584 = 514 * 256

#define K3_TB 64

static __device__ __forceinline__ float sigmoidf_(float x) { return 1.f/(1.f+expf(-x)); }

// ---------------- complex helpers + radix-4 FFT16 (W = e^{-2pi i/16}) -------
static __device__ __forceinline__ float2 cadd(float2 a, float2 b){return make_float2(a.x+b.x,a.y+b.y);}
static __device__ __forceinline__ float2 csub(float2 a, float2 b){return make_float2(a.x-b.x,a.y-b.y);}
static __device__ __forceinline__ float2 cmulc(float2 a, float cr, float ci){
  return make_float2(fmaf(a.x,cr,-a.y*ci), fmaf(a.x,ci, a.y*cr));}
static __device__ __forceinline__ float2 mulmi(float2 a){ return make_float2(a.y, -a.x); } // a * (-i)

static __device__ __forceinline__ void dft4(float2 t0,float2 t1,float2 t2,float2 t3,
                                            float2&y0,float2&y1,float2&y2,float2&y3){
  float2 A=cadd(t0,t2), B=csub(t0,t2), C=cadd(t1,t3), D=csub(t1,t3);
  y0=cadd(A,C); y2=csub(A,C);
  float2 mD=mulmi(D);
  y1=cadd(B,mD); y3=csub(B,mD);
}

static __device__ __forceinline__ void fft16(const float2* in, float2* out){
  float2 V[4][4];
  #pragma unroll
  for(int n0=0;n0<4;++n0)
    dft4(in[n0],in[n0+4],in[n0+8],in[n0+12],V[n0][0],V[n0][1],V[n0][2],V[n0][3]);
  const float C1=0.92387953251f, S1=0.38268343236f, R=0.70710678119f;
  V[1][1]=cmulc(V[1][1],  C1,-S1);
  V[1][2]=cmulc(V[1][2],   R,-R );
  V[1][3]=cmulc(V[1][3],  S1,-C1);
  V[2][1]=cmulc(V[2][1],   R,-R );
  V[2][2]=mulmi(V[2][2]);               // W16^4 = -i
  V[2][3]=cmulc(V[2][3],  -R,-R );
  V[3][1]=cmulc(V[3][1],  S1,-C1);
  V[3][2]=cmulc(V[3][2],  -R,-R );
  V[3][3]=cmulc(V[3][3], -C1, S1);      // W16^9 = -W16^1
  #pragma unroll
  for(int q=0;q<4;++q)
    dft4(V[0][q],V[1][q],V[2][q],V[3][q],out[q],out[q+4],out[q+8],out[q+12]);
}

// ---------------------------------------------------------------------------
// K0: per-frequency band table: pf[f] = (n0, w0, n1, w1)  (n* bit-cast ints)
// ---------------------------------------------------------------------------
__global__ __launch_bounds__(512) void k0_pf(const float* __restrict__ fb,
                                             float4* __restrict__ pf) {
  const int f = threadIdx.x;
  if (f >= NF) return;
  int n0 = 0, n1 = 0; float w0 = 0.f, w1 = 0.f;
  #pragma unroll 8
  for (int n = 0; n < NB; ++n) {
    float v = fb[n * NF + f];
    if (v > 0.f) { if (w0 == 0.f) { n0 = n; w0 = v; } else { n1 = n; w1 = v; } }
  }
  float4 o;
  o.x = __int_as_float(n0); o.y = w0;
  o.z = __int_as_float(n1); o.w = w1;
  pf[f] = o;
}

// ---------------------------------------------------------------------------
// K1: STFT magnitude -> fp16 mv[b][t][f]. 16 frames/block, 16 threads/frame.
// 512-pt rFFT: pack 256 complex, 16x16 four-step, radix-4 FFT16 per stage.
// ---------------------------------------------------------------------------
__global__ __launch_bounds__(256) void k1_stft(const float* __restrict__ vib,
                                               const float* __restrict__ window,
                                               f16* __restrict__ mv) {
  __shared__ float4 xs4[368];            // 1472 floats input span
  __shared__ float2 win2[256];
  __shared__ float2 w256[256];
  __shared__ float  w512c[257];
  __shared__ float  w512s[257];
  __shared__ float2 Hst[16][16][16];     // [frame][c][r^c]; aliased as Z after
  __shared__ f16    lmag[16 * 257];

  float*  xsf = (float*)xs4;
  float2 (*Zb)[256] = (float2(*)[256])Hst;

  const int tid = threadIdx.x;
  const int b   = blockIdx.x;
  const int t0  = blockIdx.y * 16;

  {
    win2[tid] = ((const float2*)window)[tid];
    float sv, cv;
    sincosf(TWO_PI * (float)tid * (1.f/256.f), &sv, &cv);
    w256[tid] = make_float2(cv, -sv);
    for (int i = tid; i < 257; i += 256) {
      float s3, c3;
      sincosf(TWO_PI * (float)i * (1.f/512.f), &s3, &c3);
      w512c[i] = c3; w512s[i] = s3;
    }
  }

  const int s0 = t0 * 64 - 256;
  for (int i = tid; i < 1472; i += 256) {
    int m = s0 + i;
    m = (m < 0) ? -m : m;
    if (m >= T_SAMP) m = 2*(T_SAMP-1) - m;
    xsf[i] = vib[(size_t)b * T_SAMP + m];
  }
  __syncthreads();

  const int fl = tid >> 4;
  const int r  = tid & 15;
  const int t  = t0 + fl;

  float2 z[16];
  const float2* xz = (const float2*)(xsf + fl * 64);
  #pragma unroll
  for (int a = 0; a < 16; ++a) {
    float2 xv = xz[r + 16*a];
    float2 wv = win2[r + 16*a];
    z[a] = make_float2(xv.x * wv.x, xv.y * wv.y);
  }

  // stage A: G = FFT16(z); twiddle by w256^{r*c}; store
  float2 G[16];
  fft16(z, G);
  #pragma unroll
  for (int c = 0; c < 16; ++c) {
    float2 tw = w256[(r*c) & 255];
    float2 h;
    h.x = G[c].x*tw.x - G[c].y*tw.y;
    h.y = G[c].x*tw.y + G[c].y*tw.x;
    Hst[fl][c][r ^ c] = h;
  }
  __syncthreads();

  // stage B
  float2 hv[16];
  #pragma unroll
  for (int q = 0; q < 16; ++q) hv[q] = Hst[fl][r][q ^ r];
  __syncthreads();
  float2 Zv[16];
  fft16(hv, Zv);
  #pragma unroll
  for (int d = 0; d < 16; ++d) Zb[fl][r + 16*d] = Zv[d];
  __syncthreads();

  // stage C: rfft untangle + |X| -> LDS (fp16)
  if (t < TFRM) {
    #pragma unroll
    for (int j = 0; j < 17; ++j) {
      int k = r + 16*j;
      if (j == 16) { if (r != 0) break; k = 256; }
      float2 A  = Zb[fl][k & 255];
      float2 Bv = Zb[fl][(256 - k) & 255];
      float Er = 0.5f*(A.x + Bv.x), Ei = 0.5f*(A.y - Bv.y);
      float Dr = 0.5f*(A.x - Bv.x), Di = 0.5f*(A.y + Bv.y);
      float tc = w512c[k], ts = w512s[k];
      float Xr = Er + tc*Di - ts*Dr;
      float Xi = Ei - tc*Dr - ts*Di;
      lmag[fl * 257 + k] = (f16)sqrtf(Xr*Xr + Xi*Xi);
    }
  }
  __syncthreads();

  const int nv = (TFRM - t0 < 16) ? (TFRM - t0) : 16;
  f16* dst = mv + ((size_t)b * TFRM + t0) * NF;
  for (int i = tid; i < nv * 257; i += 256) dst[i] = lmag[i];
}

// ---------------------------------------------------------------------------
// K2 inner helpers
// ---------------------------------------------------------------------------
static __device__ __forceinline__ float k2_init(const f16* mp, float& floorm) {
  float mn = 3.4e38f;
  #pragma unroll
  for (int tq = 0; tq < 20; ++tq) mn = fminf(mn, (float)mp[tq * NF]);
  const float initm = fmaxf(mn, 1e-5f);
  floorm = 0.5f * initm;
  return initm;
}

static __device__ __forceinline__ float k2_advance(const f16* rp, int n, float nf,
                                                   float rise, float fall, float floorm) {
  int t = 0;
  for (; t + 16 <= n; t += 16) {
    float m[16];
    #pragma unroll
    for (int q = 0; q < 16; ++q) m[q] = (float)rp[(size_t)(t + q) * NF];
    #pragma unroll
    for (int q = 0; q < 16; ++q) {
      float a = (m[q] > nf) ? rise : fall;
      nf = fmaxf(fmaf(a, m[q] - nf, nf), floorm);
    }
  }
  for (; t < n; ++t) {
    float m = (float)rp[(size_t)t * NF];
    float a = (m > nf) ? rise : fall;
    nf = fmaxf(fmaf(a, m - nf, nf), floorm);
  }
  return nf;
}

// payload: read mag from src, write vnr to dst (src==dst allowed: per-element
// read-then-write within one thread's exclusive span)
static __device__ __forceinline__ void k2_payload(const f16* src, f16* dst, int n,
                                                  float nf, float rise, float fall,
                                                  float floorm, float scale) {
  int t = 0;
  for (; t + 16 <= n; t += 16) {
    float m[16];
    #pragma unroll
    for (int q = 0; q < 16; ++q) m[q] = (float)src[(size_t)(t + q) * NF];
    #pragma unroll
    for (int q = 0; q < 16; ++q) {
      float a = (m[q] > nf) ? rise : fall;
      nf = fmaxf(fmaf(a, m[q] - nf, nf), floorm);
      float v = m[q] / fmaf(scale, nf, 1e-8f);
      dst[(size_t)(t + q) * NF] = (f16)fminf(v, 30000.f);
    }
  }
  for (; t < n; ++t) {
    float m = (float)src[(size_t)t * NF];
    float a = (m > nf) ? rise : fall;
    nf = fmaxf(fmaf(a, m - nf, nf), floorm);
    float v = m / fmaf(scale, nf, 1e-8f);
    dst[(size_t)t * NF] = (f16)fminf(v, 30000.f);
  }
}

// K2 fused (two-buffer path): warm + payload -> separate vnr buffer
__global__ __launch_bounds__(256) void k2_fused(const f16* __restrict__ mv,
                                                f16* __restrict__ vnr,
                                                const float* __restrict__ nscp,
                                                const float* __restrict__ rrp,
                                                const float* __restrict__ rfp) {
  const int gid   = blockIdx.x * 256 + threadIdx.x;
  const int chunk = gid / NCHAN;
  const int ch    = gid - chunk * NCHAN;
  const int b     = ch / NF;
  const int f     = ch - b * NF;

  const float rise  = sigmoidf_(rrp[0]);
  const float fall  = sigmoidf_(rfp[0]);
  const float scale = fabsf(nscp[0]);

  const size_t cb = (size_t)b * TFRM * NF + f;
  const f16* mp = mv + cb;

  float floorm;
  float nf = k2_init(mp, floorm);

  const int t0 = chunk * CT;
  const int t1 = (t0 + CT < TFRM) ? (t0 + CT) : TFRM;
  const int ts = (t0 > WARM) ? (t0 - WARM) : 0;

  nf = k2_advance(mp + (size_t)ts * NF, t0 - ts, nf, rise, fall, floorm);
  k2_payload(mp + (size_t)t0 * NF, vnr + cb + (size_t)t0 * NF, t1 - t0,
             nf, rise, fall, floorm, scale);
}

// K2a (in-place path): warm-up only, save {nf, floorm}
__global__ __launch_bounds__(256) void k2_warm(const f16* __restrict__ mv,
                                               float2* __restrict__ state,
                                               const float* __restrict__ rrp,
                                               const float* __restrict__ rfp) {
  const int gid   = blockIdx.x * 256 + threadIdx.x;
  const int chunk = gid / NCHAN;
  const int ch    = gid - chunk * NCHAN;
  const int b     = ch / NF;
  const int f     = ch - b * NF;

  const float rise = sigmoidf_(rrp[0]);
  const float fall = sigmoidf_(rfp[0]);

  const f16* mp = mv + (size_t)b * TFRM * NF + f;
  float floorm;
  float nf = k2_init(mp, floorm);

  const int t0 = chunk * CT;
  const int ts = (t0 > WARM) ? (t0 - WARM) : 0;
  nf = k2_advance(mp + (size_t)ts * NF, t0 - ts, nf, rise, fall, floorm);
  state[gid] = make_float2(nf, floorm);
}

// K2b (in-place path): payload in place
__global__ __launch_bounds__(256) void k2_main(f16* __restrict__ mv,
                                               const float2* __restrict__ state,
                                               const float* __restrict__ nscp,
                                               const float* __restrict__ rrp,
                                               const float* __restrict__ rfp) {
  const int gid   = blockIdx.x * 256 + threadIdx.x;
  const int chunk = gid / NCHAN;
  const int ch    = gid - chunk * NCHAN;
  const int b     = ch / NF;
  const int f     = ch - b * NF;

  const float rise  = sigmoidf_(rrp[0]);
  const float fall  = sigmoidf_(rfp[0]);
  const float scale = fabsf(nscp[0]);

  const float2 st = state[gid];
  const int t0 = chunk * CT;
  const int t1 = (t0 + CT < TFRM) ? (t0 + CT) : TFRM;

  f16* p = mv + (size_t)b * TFRM * NF + f + (size_t)t0 * NF;
  k2_payload(p, p, t1 - t0, st.x, rise, fall, st.y, scale);
}

// ---------------------------------------------------------------------------
// K3: band projection via per-f LDS-atomic binning. Block = (b, 64-t tile).
// Vectorized flat staging (ushort4) with alignment shift for odd row stride.
// MODE 0: dst = fb@mv ; MODE 1: dst = tanh(fb@mv/10)
// ---------------------------------------------------------------------------
template<int MODE>
__global__ __launch_bounds__(256) void k3_proj(const f16* __restrict__ mv,
                                               const float4* __restrict__ pf,
                                               float* __restrict__ dst) {
  __shared__ ushort4 tile4[4114];                 // 16456 halfs
  __shared__ float   bins[K3_TB][41];             // pad 41: bank stride 9
  __shared__ float4  pfl[NF];

  f16* tile = (f16*)tile4;
  const int tid = threadIdx.x;
  const int b   = blockIdx.x;
  const int t0  = blockIdx.y * K3_TB;
  const int nt  = (TFRM - t0 < K3_TB) ? (TFRM - t0) : K3_TB;

  for (int i = tid; i < K3_TB * 41; i += 256) ((float*)bins)[i] = 0.f;
  for (int i = tid; i < NF; i += 256) pfl[i] = pf[i];

  // flat staging: span = nt*257 halfs starting at element e0 (2B-aligned only)
  const size_t e0 = ((size_t)b * TFRM + t0) * NF;
  const int shift = (int)(e0 & 3);
  const ushort4* src = (const ushort4*)(mv + (e0 - shift));
  const int n4 = (nt * NF + shift + 3) >> 2;
  for (int i = tid; i < n4; i += 256) tile4[i] = src[i];
  __syncthreads();

  // compute: thread -> (t-local, f-quarter)
  const int tl = tid >> 2;
  const int q  = tid & 3;
  if (tl < nt) {
    const f16* row = tile + shift + tl * NF;
    const int fend = q * 64 + 64 + (q == 3 ? 1 : 0);   // quarter 3 covers f=256
    for (int f = q * 64; f < fend; ++f) {
      float m = (float)row[f];
      float4 w = pfl[f];
      if (w.y != 0.f) atomicAdd(&bins[tl][__float_as_int(w.x)], w.y * m);
      if (w.w != 0.f) atomicAdd(&bins[tl][__float_as_int(w.z)], w.w * m);
    }
  }
  __syncthreads();

  for (int i = tid; i < NB * K3_TB; i += 256) {
    const int n  = i >> 6;
    const int tl2 = i & 63;
    if (tl2 < nt) {
      float v = bins[tl2][n];
      if (MODE == 1) v = tanhf(v * 0.1f);
      dst[(size_t)(b * NB + n) * TFRM + t0 + tl2] = v;
    }
  }
}

// ---------------------------------------------------------------------------
// K4: kurtosis gate + per-row standardize. Block per (b,band).
// ---------------------------------------------------------------------------
__device__ __forceinline__ float blk_sum(float v, float* scr) {
  #pragma unroll
  for (int o = 32; o > 0; o >>= 1) v += __shfl_down(v, o, 64);
  const int lane = threadIdx.x & 63, w = threadIdx.x >> 6;
  __syncthreads();
  if (lane == 0) scr[w] = v;
  __syncthreads();
  return scr[0] + scr[1] + scr[2] + scr[3];
}

__global__ __launch_bounds__(256) void k4_gate(const float* band,
                                               const float* vnrb,
                                               const float* gw,
                                               const float* gb,
                                               const float* gf,
                                               float* feat) {
  __shared__ float scr[4];
  const int bid = blockIdx.x;
  const int b = bid / NB, n = bid - b * NB;
  const size_t base = (size_t)(b * NB + n) * TFRM;
  const float* row = band + base;
  const float* vr  = vnrb + base;
  const int tid = threadIdx.x;

  float xl[16];
  float s1 = 0.f;
  #pragma unroll
  for (int q = 0; q < 16; ++q) {
    int i = tid + q * 256;
    xl[q] = (i < TFRM) ? row[i] : 0.f;
    s1 += xl[q];
  }
  s1 = blk_sum(s1, scr);
  const float mu = s1 * (1.f / 4001.f);

  float s2 = 0.f, s4 = 0.f;
  #pragma unroll
  for (int q = 0; q < 16; ++q) {
    int i = tid + q * 256;
    if (i < TFRM) { float d = xl[q] - mu; float d2 = d * d; s2 += d2; s4 += d2 * d2; }
  }
  s2 = blk_sum(s2, scr);
  s4 = blk_sum(s4, scr);
  const float var  = fmaxf(s2 * (1.f / 4001.f), 1e-8f);
  const float kurt = (s4 * (1.f / 4001.f)) / (var * var + 1e-8f);
  const float kn   = (kurt - 3.f) * (1.f / 3.f);

  const float fl = sigmoidf_(gf[n]);
  float g0 = sigmoidf_(fmaf(gw[n], kn, gb[n]));
  g0 = g0 * (1.f - fl) + fl;

  float sy = 0.f;
  #pragma unroll
  for (int q = 0; q < 16; ++q) {
    int i = tid + q * 256;
    if (i < TFRM) {
      float y = xl[q] * g0 * (0.5f + 0.5f * vr[i]);
      xl[q] = y; sy += y;
    } else xl[q] = 0.f;
  }
  sy = blk_sum(sy, scr);
  const float mean = sy * (1.f / 4001.f);

  float sv = 0.f;
  #pragma unroll
  for (int q = 0; q < 16; ++q) {
    int i = tid + q * 256;
    if (i < TFRM) { float d = xl[q] - mean; sv += d * d; }
  }
  sv = blk_sum(sv, scr);
  const float rstd = 1.f / sqrtf(sv * (1.f / 4001.f) + 1e-5f);

  #pragma unroll
  for (int q = 0; q < 16; ++q) {
    int i = tid + q * 256;
    if (i < TFRM) feat[base + i] = (xl[q] - mean) * rstd;
  }
}

// ---------------------------------------------------------------------------
extern "C" void kernel_launch(void* const* d_in, const int* in_sizes, int n_in,
                              void* d_out, int out_size, void* d_ws, size_t ws_size,
                              hipStream_t stream) {
  const float* vib = (const float*)d_in[0];
  const float* fb  = (const float*)d_in[1];
  const float* win = (const float*)d_in[2];
  const float* nsc = (const float*)d_in[3];
  const float* rr  = (const float*)d_in[4];
  const float* rf  = (const float*)d_in[5];
  const float* gw  = (const float*)d_in[6];
  const float* gb  = (const float*)d_in[7];
  const float* gf  = (const float*)d_in[8];
  float* out = (float*)d_out;
  (void)in_sizes; (void)n_in; (void)out_size;

  if (ws_size < IN_PLACE_NEED) return;   // diagnostic clean-fail

  f16*    mv   = (f16*)d_ws;
  float4* pf   = (float4*)((char*)d_ws + MV_BYTES);
  f16*    vnr2 = (f16*)((char*)d_ws + MV_BYTES + PF_BYTES);
  float2* state = (float2*)(out + OFFOUT);   // in-place path: parked in vnrb
                                             // region, consumed before k3<1>
  const bool twobuf = (ws_size >= TWO_BUF_NEED);

  hipLaunchKernelGGL(k0_pf,   dim3(1),       dim3(512), 0, stream, fb, pf);
  hipLaunchKernelGGL(k1_stft, dim3(32, 251), dim3(256), 0, stream, vib, win, mv);

  if (twobuf) {
    hipLaunchKernelGGL(k2_fused,   dim3(514),    dim3(256), 0, stream, mv, vnr2, nsc, rr, rf);
    hipLaunchKernelGGL(k3_proj<0>, dim3(32, 63), dim3(256), 0, stream, mv,   pf, out);
    hipLaunchKernelGGL(k3_proj<1>, dim3(32, 63), dim3(256), 0, stream, vnr2, pf, out + OFFOUT);
  } else {
    hipLaunchKernelGGL(k2_warm,    dim3(514),    dim3(256), 0, stream, mv, state, rr, rf);
    hipLaunchKernelGGL(k3_proj<0>, dim3(32, 63), dim3(256), 0, stream, mv, pf, out);
    hipLaunchKernelGGL(k2_main,    dim3(514),    dim3(256), 0, stream, mv, state, nsc, rr, rf);
    hipLaunchKernelGGL(k3_proj<1>, dim3(32, 63), dim3(256), 0, stream, mv, pf, out + OFFOUT);
  }

  hipLaunchKernelGGL(k4_gate, dim3(1280), dim3(256), 0, stream,
                     out, out + OFFOUT, gw, gb, gf, out);
}

// Round 4
// 481.674 us; speedup vs baseline: 1.9688x; 1.9688x over previous
//
#include <hip/hip_runtime.h>
#include <math.h>
#include <cstddef>

#define T_SAMP 256000
#define TFRM   4001
#define NF     257
#define NB     40
#define NBATCH 32
#define OFFOUT ((size_t)NBATCH*NB*TFRM)
#define TWO_PI 6.283185307179586f

typedef _Float16 f16;

#define MV_ELEMS  ((size_t)NBATCH * TFRM * NF)            // 32,904,224 halfs
#define MV_BYTES  (MV_ELEMS * 2)                          // 65,808,448
#define PF_BYTES  ((size_t)16384)
#define IN_PLACE_NEED (MV_BYTES + PF_BYTES)               // < proven 66,334,784
#define TWO_BUF_NEED  (2*MV_BYTES + PF_BYTES)

// K2 chunking
#define CHUNKS 16
#define CT     251            // ceil(4001/16)
#define WARM   288            // 0.9526^288 ~ 9e-7 (< fp16 noise)
#define NCHAN  (NBATCH * NF)  // 8224

static __device__ __forceinline__ float sigmoidf_(float x) { return 1.f/(1.f+expf(-x)); }

// ---------------- complex helpers + radix-4 FFT16 (W = e^{-2pi i/16}) -------
static __device__ __forceinline__ float2 cadd(float2 a, float2 b){return make_float2(a.x+b.x,a.y+b.y);}
static __device__ __forceinline__ float2 csub(float2 a, float2 b){return make_float2(a.x-b.x,a.y-b.y);}
static __device__ __forceinline__ float2 cmulc(float2 a, float cr, float ci){
  return make_float2(fmaf(a.x,cr,-a.y*ci), fmaf(a.x,ci, a.y*cr));}
static __device__ __forceinline__ float2 mulmi(float2 a){ return make_float2(a.y, -a.x); } // a * (-i)

static __device__ __forceinline__ void dft4(float2 t0,float2 t1,float2 t2,float2 t3,
                                            float2&y0,float2&y1,float2&y2,float2&y3){
  float2 A=cadd(t0,t2), B=csub(t0,t2), C=cadd(t1,t3), D=csub(t1,t3);
  y0=cadd(A,C); y2=csub(A,C);
  float2 mD=mulmi(D);
  y1=cadd(B,mD); y3=csub(B,mD);
}

static __device__ __forceinline__ void fft16(const float2* in, float2* out){
  float2 V[4][4];
  #pragma unroll
  for(int n0=0;n0<4;++n0)
    dft4(in[n0],in[n0+4],in[n0+8],in[n0+12],V[n0][0],V[n0][1],V[n0][2],V[n0][3]);
  const float C1=0.92387953251f, S1=0.38268343236f, R=0.70710678119f;
  V[1][1]=cmulc(V[1][1],  C1,-S1);
  V[1][2]=cmulc(V[1][2],   R,-R );
  V[1][3]=cmulc(V[1][3],  S1,-C1);
  V[2][1]=cmulc(V[2][1],   R,-R );
  V[2][2]=mulmi(V[2][2]);               // W16^4 = -i
  V[2][3]=cmulc(V[2][3],  -R,-R );
  V[3][1]=cmulc(V[3][1],  S1,-C1);
  V[3][2]=cmulc(V[3][2],  -R,-R );
  V[3][3]=cmulc(V[3][3], -C1, S1);      // W16^9 = -W16^1
  #pragma unroll
  for(int q=0;q<4;++q)
    dft4(V[0][q],V[1][q],V[2][q],V[3][q],out[q],out[q+4],out[q+8],out[q+12]);
}

// ---------------------------------------------------------------------------
// K0: per-frequency band table: pf[f] = (n0, w0, n1, w1). Active bands at any
// f are consecutive (n0, n0+1) and n0(f) is non-decreasing (triangular fb).
// ---------------------------------------------------------------------------
__global__ __launch_bounds__(512) void k0_pf(const float* __restrict__ fb,
                                             float4* __restrict__ pf) {
  const int f = threadIdx.x;
  if (f >= NF) return;
  int n0 = 0, n1 = 0; float w0 = 0.f, w1 = 0.f;
  #pragma unroll 8
  for (int n = 0; n < NB; ++n) {
    float v = fb[n * NF + f];
    if (v > 0.f) { if (w0 == 0.f) { n0 = n; w0 = v; } else { n1 = n; w1 = v; } }
  }
  float4 o;
  o.x = __int_as_float(n0); o.y = w0;
  o.z = __int_as_float(n1); o.w = w1;
  pf[f] = o;
}

// ---------------------------------------------------------------------------
// K1: STFT magnitude -> fp16 mv[b][t][f]. 16 frames/block, 16 threads/frame.
// 512-pt rFFT: pack 256 complex, 16x16 four-step, radix-4 FFT16 per stage.
// ---------------------------------------------------------------------------
__global__ __launch_bounds__(256) void k1_stft(const float* __restrict__ vib,
                                               const float* __restrict__ window,
                                               f16* __restrict__ mv) {
  __shared__ float4 xs4[368];            // 1472 floats input span
  __shared__ float2 win2[256];
  __shared__ float2 w256[256];
  __shared__ float  w512c[257];
  __shared__ float  w512s[257];
  __shared__ float2 Hst[16][16][16];     // [frame][c][r^c]; aliased as Z after
  __shared__ f16    lmag[16 * 257];

  float*  xsf = (float*)xs4;
  float2 (*Zb)[256] = (float2(*)[256])Hst;

  const int tid = threadIdx.x;
  const int b   = blockIdx.x;
  const int t0  = blockIdx.y * 16;

  {
    win2[tid] = ((const float2*)window)[tid];
    float sv, cv;
    sincosf(TWO_PI * (float)tid * (1.f/256.f), &sv, &cv);
    w256[tid] = make_float2(cv, -sv);
    for (int i = tid; i < 257; i += 256) {
      float s3, c3;
      sincosf(TWO_PI * (float)i * (1.f/512.f), &s3, &c3);
      w512c[i] = c3; w512s[i] = s3;
    }
  }

  const int s0 = t0 * 64 - 256;
  for (int i = tid; i < 1472; i += 256) {
    int m = s0 + i;
    m = (m < 0) ? -m : m;
    if (m >= T_SAMP) m = 2*(T_SAMP-1) - m;
    xsf[i] = vib[(size_t)b * T_SAMP + m];
  }
  __syncthreads();

  const int fl = tid >> 4;
  const int r  = tid & 15;
  const int t  = t0 + fl;

  float2 z[16];
  const float2* xz = (const float2*)(xsf + fl * 64);
  #pragma unroll
  for (int a = 0; a < 16; ++a) {
    float2 xv = xz[r + 16*a];
    float2 wv = win2[r + 16*a];
    z[a] = make_float2(xv.x * wv.x, xv.y * wv.y);
  }

  // stage A: G = FFT16(z); twiddle by w256^{r*c}; store
  float2 G[16];
  fft16(z, G);
  #pragma unroll
  for (int c = 0; c < 16; ++c) {
    float2 tw = w256[(r*c) & 255];
    float2 h;
    h.x = G[c].x*tw.x - G[c].y*tw.y;
    h.y = G[c].x*tw.y + G[c].y*tw.x;
    Hst[fl][c][r ^ c] = h;
  }
  __syncthreads();

  // stage B
  float2 hv[16];
  #pragma unroll
  for (int q = 0; q < 16; ++q) hv[q] = Hst[fl][r][q ^ r];
  __syncthreads();
  float2 Zv[16];
  fft16(hv, Zv);
  #pragma unroll
  for (int d = 0; d < 16; ++d) Zb[fl][r + 16*d] = Zv[d];
  __syncthreads();

  // stage C: rfft untangle + |X| -> LDS (fp16)
  if (t < TFRM) {
    #pragma unroll
    for (int j = 0; j < 17; ++j) {
      int k = r + 16*j;
      if (j == 16) { if (r != 0) break; k = 256; }
      float2 A  = Zb[fl][k & 255];
      float2 Bv = Zb[fl][(256 - k) & 255];
      float Er = 0.5f*(A.x + Bv.x), Ei = 0.5f*(A.y - Bv.y);
      float Dr = 0.5f*(A.x - Bv.x), Di = 0.5f*(A.y + Bv.y);
      float tc = w512c[k], ts = w512s[k];
      float Xr = Er + tc*Di - ts*Dr;
      float Xi = Ei - tc*Dr - ts*Di;
      lmag[fl * 257 + k] = (f16)sqrtf(Xr*Xr + Xi*Xi);
    }
  }
  __syncthreads();

  const int nv = (TFRM - t0 < 16) ? (TFRM - t0) : 16;
  f16* dst = mv + ((size_t)b * TFRM + t0) * NF;
  for (int i = tid; i < nv * 257; i += 256) dst[i] = lmag[i];
}

// ---------------------------------------------------------------------------
// K2 inner helpers
// ---------------------------------------------------------------------------
static __device__ __forceinline__ float k2_init(const f16* mp, float& floorm) {
  float mn = 3.4e38f;
  #pragma unroll
  for (int tq = 0; tq < 20; ++tq) mn = fminf(mn, (float)mp[tq * NF]);
  const float initm = fmaxf(mn, 1e-5f);
  floorm = 0.5f * initm;
  return initm;
}

static __device__ __forceinline__ float k2_advance(const f16* rp, int n, float nf,
                                                   float rise, float fall, float floorm) {
  int t = 0;
  for (; t + 16 <= n; t += 16) {
    float m[16];
    #pragma unroll
    for (int q = 0; q < 16; ++q) m[q] = (float)rp[(size_t)(t + q) * NF];
    #pragma unroll
    for (int q = 0; q < 16; ++q) {
      float a = (m[q] > nf) ? rise : fall;
      nf = fmaxf(fmaf(a, m[q] - nf, nf), floorm);
    }
  }
  for (; t < n; ++t) {
    float m = (float)rp[(size_t)t * NF];
    float a = (m > nf) ? rise : fall;
    nf = fmaxf(fmaf(a, m - nf, nf), floorm);
  }
  return nf;
}

static __device__ __forceinline__ void k2_payload(const f16* src, f16* dst, int n,
                                                  float nf, float rise, float fall,
                                                  float floorm, float scale) {
  int t = 0;
  for (; t + 16 <= n; t += 16) {
    float m[16];
    #pragma unroll
    for (int q = 0; q < 16; ++q) m[q] = (float)src[(size_t)(t + q) * NF];
    #pragma unroll
    for (int q = 0; q < 16; ++q) {
      float a = (m[q] > nf) ? rise : fall;
      nf = fmaxf(fmaf(a, m[q] - nf, nf), floorm);
      float v = m[q] / fmaf(scale, nf, 1e-8f);
      dst[(size_t)(t + q) * NF] = (f16)fminf(v, 30000.f);
    }
  }
  for (; t < n; ++t) {
    float m = (float)src[(size_t)t * NF];
    float a = (m > nf) ? rise : fall;
    nf = fmaxf(fmaf(a, m - nf, nf), floorm);
    float v = m / fmaf(scale, nf, 1e-8f);
    dst[(size_t)t * NF] = (f16)fminf(v, 30000.f);
  }
}

// K2 fused (two-buffer path)
__global__ __launch_bounds__(256) void k2_fused(const f16* __restrict__ mv,
                                                f16* __restrict__ vnr,
                                                const float* __restrict__ nscp,
                                                const float* __restrict__ rrp,
                                                const float* __restrict__ rfp) {
  const int gid   = blockIdx.x * 256 + threadIdx.x;
  const int chunk = gid / NCHAN;
  const int ch    = gid - chunk * NCHAN;
  const int b     = ch / NF;
  const int f     = ch - b * NF;

  const float rise  = sigmoidf_(rrp[0]);
  const float fall  = sigmoidf_(rfp[0]);
  const float scale = fabsf(nscp[0]);

  const size_t cb = (size_t)b * TFRM * NF + f;
  const f16* mp = mv + cb;

  float floorm;
  float nf = k2_init(mp, floorm);

  const int t0 = chunk * CT;
  const int t1 = (t0 + CT < TFRM) ? (t0 + CT) : TFRM;
  const int ts = (t0 > WARM) ? (t0 - WARM) : 0;

  nf = k2_advance(mp + (size_t)ts * NF, t0 - ts, nf, rise, fall, floorm);
  k2_payload(mp + (size_t)t0 * NF, vnr + cb + (size_t)t0 * NF, t1 - t0,
             nf, rise, fall, floorm, scale);
}

// K2a (in-place path)
__global__ __launch_bounds__(256) void k2_warm(const f16* __restrict__ mv,
                                               float2* __restrict__ state,
                                               const float* __restrict__ rrp,
                                               const float* __restrict__ rfp) {
  const int gid   = blockIdx.x * 256 + threadIdx.x;
  const int chunk = gid / NCHAN;
  const int ch    = gid - chunk * NCHAN;
  const int b     = ch / NF;
  const int f     = ch - b * NF;

  const float rise = sigmoidf_(rrp[0]);
  const float fall = sigmoidf_(rfp[0]);

  const f16* mp = mv + (size_t)b * TFRM * NF + f;
  float floorm;
  float nf = k2_init(mp, floorm);

  const int t0 = chunk * CT;
  const int ts = (t0 > WARM) ? (t0 - WARM) : 0;
  nf = k2_advance(mp + (size_t)ts * NF, t0 - ts, nf, rise, fall, floorm);
  state[gid] = make_float2(nf, floorm);
}

// K2b (in-place path)
__global__ __launch_bounds__(256) void k2_main(f16* __restrict__ mv,
                                               const float2* __restrict__ state,
                                               const float* __restrict__ nscp,
                                               const float* __restrict__ rrp,
                                               const float* __restrict__ rfp) {
  const int gid   = blockIdx.x * 256 + threadIdx.x;
  const int chunk = gid / NCHAN;
  const int ch    = gid - chunk * NCHAN;
  const int b     = ch / NF;
  const int f     = ch - b * NF;

  const float rise  = sigmoidf_(rrp[0]);
  const float fall  = sigmoidf_(rfp[0]);
  const float scale = fabsf(nscp[0]);

  const float2 st = state[gid];
  const int t0 = chunk * CT;
  const int t1 = (t0 + CT < TFRM) ? (t0 + CT) : TFRM;

  f16* p = mv + (size_t)b * TFRM * NF + f + (size_t)t0 * NF;
  k2_payload(p, p, t1 - t0, st.x, rise, fall, st.y, scale);
}

// ---------------------------------------------------------------------------
// K3: ordered band sweep, NO atomics. Block = 64 threads = 64 t-rows, flat
// contiguous staging. Per thread: sweep f ascending keeping 2 register accs
// (bands cur, cur+1); flush on band advance (uniform across lanes, coalesced
// stores). Zero-fill skipped/empty bands via monotone write cursor.
// MODE 0: dst = fb@mv ; MODE 1: dst = tanh(fb@mv/10)
// ---------------------------------------------------------------------------
template<int MODE>
__global__ __launch_bounds__(64) void k3_sweep(const f16* __restrict__ mv,
                                               const float4* __restrict__ pf,
                                               float* __restrict__ dst) {
  __shared__ ushort4 tile4[4114];        // 64*257 halfs + shift slop
  __shared__ float4  pfl[NF];

  f16* tile = (f16*)tile4;
  const int tid = threadIdx.x;
  const int b   = blockIdx.x;
  const int t0  = blockIdx.y * 64;
  const int nt  = (TFRM - t0 < 64) ? (TFRM - t0) : 64;

  for (int i = tid; i < NF; i += 64) pfl[i] = pf[i];

  const size_t e0 = ((size_t)b * TFRM + t0) * NF;
  const int shift = (int)(e0 & 3);
  const ushort4* src = (const ushort4*)(mv + (e0 - shift));
  const int n4 = (nt * NF + shift + 3) >> 2;
  for (int i = tid; i < n4; i += 64) tile4[i] = src[i];
  __syncthreads();

  const bool act = tid < nt;
  const f16* row = tile + shift + tid * NF;
  float* op = dst + (size_t)b * NB * TFRM + t0 + tid;   // + n*TFRM per band

  float accA = 0.f, accB = 0.f;
  int cur = -2, nw = 0;

#define K3_STORE(n_, v_) do { \
    float vv = (v_); if (MODE == 1) vv = tanhf(vv * 0.1f); \
    if (act) op[(size_t)(n_) * TFRM] = vv; } while (0)
#define K3_EMIT(n_, v_) do { int nn = (n_); \
    while (nw < nn && nw < NB) { if (act) op[(size_t)nw * TFRM] = 0.f; ++nw; } \
    if (nn < NB) { K3_STORE(nn, v_); nw = nn + 1; } } while (0)

  for (int f = 0; f < NF; ++f) {
    float4 w = pfl[f];
    if (w.y == 0.f) continue;                 // no active band (f=0 only)
    const int n0 = __float_as_int(w.x);
    if (n0 != cur) {                          // uniform across lanes
      if (cur >= 0) {
        if (n0 == cur + 1) { K3_EMIT(cur, accA); accA = accB; accB = 0.f; }
        else { K3_EMIT(cur, accA); K3_EMIT(cur + 1, accB); accA = 0.f; accB = 0.f; }
      }
      cur = n0;
    }
    const float m = (float)row[f];
    accA = fmaf(w.y, m, accA);
    accB = fmaf(w.w, m, accB);
  }
  if (cur >= 0) { K3_EMIT(cur, accA); K3_EMIT(cur + 1, accB); }
  while (nw < NB) { if (act) op[(size_t)nw * TFRM] = 0.f; ++nw; }
#undef K3_EMIT
#undef K3_STORE
}

// ---------------------------------------------------------------------------
// K4: kurtosis gate + per-row standardize. Block per (b,band).
// ---------------------------------------------------------------------------
__device__ __forceinline__ float blk_sum(float v, float* scr) {
  #pragma unroll
  for (int o = 32; o > 0; o >>= 1) v += __shfl_down(v, o, 64);
  const int lane = threadIdx.x & 63, w = threadIdx.x >> 6;
  __syncthreads();
  if (lane == 0) scr[w] = v;
  __syncthreads();
  return scr[0] + scr[1] + scr[2] + scr[3];
}

__global__ __launch_bounds__(256) void k4_gate(const float* band,
                                               const float* vnrb,
                                               const float* gw,
                                               const float* gb,
                                               const float* gf,
                                               float* feat) {
  __shared__ float scr[4];
  const int bid = blockIdx.x;
  const int b = bid / NB, n = bid - b * NB;
  const size_t base = (size_t)(b * NB + n) * TFRM;
  const float* row = band + base;
  const float* vr  = vnrb + base;
  const int tid = threadIdx.x;

  float xl[16];
  float s1 = 0.f;
  #pragma unroll
  for (int q = 0; q < 16; ++q) {
    int i = tid + q * 256;
    xl[q] = (i < TFRM) ? row[i] : 0.f;
    s1 += xl[q];
  }
  s1 = blk_sum(s1, scr);
  const float mu = s1 * (1.f / 4001.f);

  float s2 = 0.f, s4 = 0.f;
  #pragma unroll
  for (int q = 0; q < 16; ++q) {
    int i = tid + q * 256;
    if (i < TFRM) { float d = xl[q] - mu; float d2 = d * d; s2 += d2; s4 += d2 * d2; }
  }
  s2 = blk_sum(s2, scr);
  s4 = blk_sum(s4, scr);
  const float var  = fmaxf(s2 * (1.f / 4001.f), 1e-8f);
  const float kurt = (s4 * (1.f / 4001.f)) / (var * var + 1e-8f);
  const float kn   = (kurt - 3.f) * (1.f / 3.f);

  const float fl = sigmoidf_(gf[n]);
  float g0 = sigmoidf_(fmaf(gw[n], kn, gb[n]));
  g0 = g0 * (1.f - fl) + fl;

  float sy = 0.f;
  #pragma unroll
  for (int q = 0; q < 16; ++q) {
    int i = tid + q * 256;
    if (i < TFRM) {
      float y = xl[q] * g0 * (0.5f + 0.5f * vr[i]);
      xl[q] = y; sy += y;
    } else xl[q] = 0.f;
  }
  sy = blk_sum(sy, scr);
  const float mean = sy * (1.f / 4001.f);

  float sv = 0.f;
  #pragma unroll
  for (int q = 0; q < 16; ++q) {
    int i = tid + q * 256;
    if (i < TFRM) { float d = xl[q] - mean; sv += d * d; }
  }
  sv = blk_sum(sv, scr);
  const float rstd = 1.f / sqrtf(sv * (1.f / 4001.f) + 1e-5f);

  #pragma unroll
  for (int q = 0; q < 16; ++q) {
    int i = tid + q * 256;
    if (i < TFRM) feat[base + i] = (xl[q] - mean) * rstd;
  }
}

// ---------------------------------------------------------------------------
extern "C" void kernel_launch(void* const* d_in, const int* in_sizes, int n_in,
                              void* d_out, int out_size, void* d_ws, size_t ws_size,
                              hipStream_t stream) {
  const float* vib = (const float*)d_in[0];
  const float* fb  = (const float*)d_in[1];
  const float* win = (const float*)d_in[2];
  const float* nsc = (const float*)d_in[3];
  const float* rr  = (const float*)d_in[4];
  const float* rf  = (const float*)d_in[5];
  const float* gw  = (const float*)d_in[6];
  const float* gb  = (const float*)d_in[7];
  const float* gf  = (const float*)d_in[8];
  float* out = (float*)d_out;
  (void)in_sizes; (void)n_in; (void)out_size;

  if (ws_size < IN_PLACE_NEED) return;   // diagnostic clean-fail

  f16*    mv   = (f16*)d_ws;
  float4* pf   = (float4*)((char*)d_ws + MV_BYTES);
  f16*    vnr2 = (f16*)((char*)d_ws + MV_BYTES + PF_BYTES);
  float2* state = (float2*)(out + OFFOUT);   // in-place path: parked in vnrb
                                             // region, consumed before k3<1>
  const bool twobuf = (ws_size >= TWO_BUF_NEED);

  hipLaunchKernelGGL(k0_pf,   dim3(1),       dim3(512), 0, stream, fb, pf);
  hipLaunchKernelGGL(k1_stft, dim3(32, 251), dim3(256), 0, stream, vib, win, mv);

  if (twobuf) {
    hipLaunchKernelGGL(k2_fused,    dim3(514),    dim3(256), 0, stream, mv, vnr2, nsc, rr, rf);
    hipLaunchKernelGGL(k3_sweep<0>, dim3(32, 63), dim3(64),  0, stream, mv,   pf, out);
    hipLaunchKernelGGL(k3_sweep<1>, dim3(32, 63), dim3(64),  0, stream, vnr2, pf, out + OFFOUT);
  } else {
    hipLaunchKernelGGL(k2_warm,     dim3(514),    dim3(256), 0, stream, mv, state, rr, rf);
    hipLaunchKernelGGL(k3_sweep<0>, dim3(32, 63), dim3(64),  0, stream, mv, pf, out);
    hipLaunchKernelGGL(k2_main,     dim3(514),    dim3(256), 0, stream, mv, state, nsc, rr, rf);
    hipLaunchKernelGGL(k3_sweep<1>, dim3(32, 63), dim3(64),  0, stream, mv, pf, out + OFFOUT);
  }

  hipLaunchKernelGGL(k4_gate, dim3(1280), dim3(256), 0, stream,
                     out, out + OFFOUT, gw, gb, gf, out);
}

// Round 5
// 478.392 us; speedup vs baseline: 1.9823x; 1.0069x over previous
//
#include <hip/hip_runtime.h>
#include <math.h>
#include <cstddef>

#define T_SAMP 256000
#define TFRM   4001
#define NF     257
#define NFP    258            // padded row stride (516 B -> every row 4B-aligned)
#define NB     40
#define NBATCH 32
#define OFFOUT ((size_t)NBATCH*NB*TFRM)
#define TWO_PI 6.283185307179586f

typedef _Float16 f16;
typedef _Float16 f16x2 __attribute__((ext_vector_type(2)));

#define MV_ELEMS  ((size_t)NBATCH * TFRM * NFP)           // 33,032,256 halfs
#define MV_BYTES  (MV_ELEMS * 2)                          // 66,064,512
#define PF_BYTES  ((size_t)16384)
#define IN_PLACE_NEED (MV_BYTES + PF_BYTES)               // 66,080,896 <= proven 66,334,784
#define TWO_BUF_NEED  (2*MV_BYTES + PF_BYTES)

// K2 chunking
#define CHUNKS 16
#define CT     251            // ceil(4001/16)
#define WARM   288            // 0.9526^288 ~ 9e-7 (< fp16 noise)
#define NCHAN  (NBATCH * NF)  // 8224

static __device__ __forceinline__ float sigmoidf_(float x) { return 1.f/(1.f+expf(-x)); }

// ---------------- complex helpers + radix-4 FFT16 (W = e^{-2pi i/16}) -------
static __device__ __forceinline__ float2 cadd(float2 a, float2 b){return make_float2(a.x+b.x,a.y+b.y);}
static __device__ __forceinline__ float2 csub(float2 a, float2 b){return make_float2(a.x-b.x,a.y-b.y);}
static __device__ __forceinline__ float2 cmulc(float2 a, float cr, float ci){
  return make_float2(fmaf(a.x,cr,-a.y*ci), fmaf(a.x,ci, a.y*cr));}
static __device__ __forceinline__ float2 mulmi(float2 a){ return make_float2(a.y, -a.x); } // a * (-i)

static __device__ __forceinline__ void dft4(float2 t0,float2 t1,float2 t2,float2 t3,
                                            float2&y0,float2&y1,float2&y2,float2&y3){
  float2 A=cadd(t0,t2), B=csub(t0,t2), C=cadd(t1,t3), D=csub(t1,t3);
  y0=cadd(A,C); y2=csub(A,C);
  float2 mD=mulmi(D);
  y1=cadd(B,mD); y3=csub(B,mD);
}

static __device__ __forceinline__ void fft16(const float2* in, float2* out){
  float2 V[4][4];
  #pragma unroll
  for(int n0=0;n0<4;++n0)
    dft4(in[n0],in[n0+4],in[n0+8],in[n0+12],V[n0][0],V[n0][1],V[n0][2],V[n0][3]);
  const float C1=0.92387953251f, S1=0.38268343236f, R=0.70710678119f;
  V[1][1]=cmulc(V[1][1],  C1,-S1);
  V[1][2]=cmulc(V[1][2],   R,-R );
  V[1][3]=cmulc(V[1][3],  S1,-C1);
  V[2][1]=cmulc(V[2][1],   R,-R );
  V[2][2]=mulmi(V[2][2]);               // W16^4 = -i
  V[2][3]=cmulc(V[2][3],  -R,-R );
  V[3][1]=cmulc(V[3][1],  S1,-C1);
  V[3][2]=cmulc(V[3][2],  -R,-R );
  V[3][3]=cmulc(V[3][3], -C1, S1);      // W16^9 = -W16^1
  #pragma unroll
  for(int q=0;q<4;++q)
    dft4(V[0][q],V[1][q],V[2][q],V[3][q],out[q],out[q+4],out[q+8],out[q+12]);
}

// ---------------------------------------------------------------------------
// K0: per-frequency band table, NFP entries; entry 257 (pad) zeroed.
// ---------------------------------------------------------------------------
__global__ __launch_bounds__(512) void k0_pf(const float* __restrict__ fb,
                                             float4* __restrict__ pf) {
  const int f = threadIdx.x;
  if (f >= NFP) return;
  if (f == NFP - 1) { pf[f] = make_float4(0.f, 0.f, 0.f, 0.f); return; }
  int n0 = 0, n1 = 0; float w0 = 0.f, w1 = 0.f;
  #pragma unroll 8
  for (int n = 0; n < NB; ++n) {
    float v = fb[n * NF + f];
    if (v > 0.f) { if (w0 == 0.f) { n0 = n; w0 = v; } else { n1 = n; w1 = v; } }
  }
  float4 o;
  o.x = __int_as_float(n0); o.y = w0;
  o.z = __int_as_float(n1); o.w = w1;
  pf[f] = o;
}

// ---------------------------------------------------------------------------
// K1: STFT magnitude -> fp16 mv[b][t][NFP]. 16 frames/block, 16 thr/frame.
// ---------------------------------------------------------------------------
__global__ __launch_bounds__(256) void k1_stft(const float* __restrict__ vib,
                                               const float* __restrict__ window,
                                               f16* __restrict__ mv) {
  __shared__ float4 xs4[368];            // 1472 floats input span
  __shared__ float2 win2[256];
  __shared__ float2 w256[256];
  __shared__ float  w512c[257];
  __shared__ float  w512s[257];
  __shared__ float2 Hst[16][16][16];     // [frame][c][r^c]; aliased as Z after
  __shared__ f16    lmag[16 * NFP];      // padded rows (16B-aligned copy src)

  float*  xsf = (float*)xs4;
  float2 (*Zb)[256] = (float2(*)[256])Hst;

  const int tid = threadIdx.x;
  const int b   = blockIdx.x;
  const int t0  = blockIdx.y * 16;

  {
    win2[tid] = ((const float2*)window)[tid];
    float sv, cv;
    sincosf(TWO_PI * (float)tid * (1.f/256.f), &sv, &cv);
    w256[tid] = make_float2(cv, -sv);
    for (int i = tid; i < 257; i += 256) {
      float s3, c3;
      sincosf(TWO_PI * (float)i * (1.f/512.f), &s3, &c3);
      w512c[i] = c3; w512s[i] = s3;
    }
  }

  const int s0 = t0 * 64 - 256;
  for (int i = tid; i < 1472; i += 256) {
    int m = s0 + i;
    m = (m < 0) ? -m : m;
    if (m >= T_SAMP) m = 2*(T_SAMP-1) - m;
    xsf[i] = vib[(size_t)b * T_SAMP + m];
  }
  __syncthreads();

  const int fl = tid >> 4;
  const int r  = tid & 15;
  const int t  = t0 + fl;

  float2 z[16];
  const float2* xz = (const float2*)(xsf + fl * 64);
  #pragma unroll
  for (int a = 0; a < 16; ++a) {
    float2 xv = xz[r + 16*a];
    float2 wv = win2[r + 16*a];
    z[a] = make_float2(xv.x * wv.x, xv.y * wv.y);
  }

  // stage A: G = FFT16(z); twiddle; store
  float2 G[16];
  fft16(z, G);
  #pragma unroll
  for (int c = 0; c < 16; ++c) {
    float2 tw = w256[(r*c) & 255];
    float2 h;
    h.x = G[c].x*tw.x - G[c].y*tw.y;
    h.y = G[c].x*tw.y + G[c].y*tw.x;
    Hst[fl][c][r ^ c] = h;
  }
  __syncthreads();

  // stage B
  float2 hv[16];
  #pragma unroll
  for (int q = 0; q < 16; ++q) hv[q] = Hst[fl][r][q ^ r];
  __syncthreads();
  float2 Zv[16];
  fft16(hv, Zv);
  #pragma unroll
  for (int d = 0; d < 16; ++d) Zb[fl][r + 16*d] = Zv[d];
  __syncthreads();

  // stage C: rfft untangle + |X| -> LDS (fp16)
  if (t < TFRM) {
    #pragma unroll
    for (int j = 0; j < 17; ++j) {
      int k = r + 16*j;
      if (j == 16) { if (r != 0) break; k = 256; }
      float2 A  = Zb[fl][k & 255];
      float2 Bv = Zb[fl][(256 - k) & 255];
      float Er = 0.5f*(A.x + Bv.x), Ei = 0.5f*(A.y - Bv.y);
      float Dr = 0.5f*(A.x - Bv.x), Di = 0.5f*(A.y + Bv.y);
      float tc = w512c[k], ts = w512s[k];
      float Xr = Er + tc*Di - ts*Dr;
      float Xi = Ei - tc*Dr - ts*Di;
      lmag[fl * NFP + k] = (f16)sqrtf(Xr*Xr + Xi*Xi);
    }
  }
  __syncthreads();

  // linear coalesced copy-out (uint; both src and dst rows 4B-aligned)
  const int nv = (TFRM - t0 < 16) ? (TFRM - t0) : 16;
  const uint* ls = (const uint*)lmag;
  uint* dst32 = (uint*)(mv + ((size_t)b * TFRM + t0) * NFP);
  const int n32 = nv * (NFP / 2);
  for (int i = tid; i < n32; i += 256) dst32[i] = ls[i];
}

// ---------------------------------------------------------------------------
// K2 inner helpers (stride NFP)
// ---------------------------------------------------------------------------
static __device__ __forceinline__ float k2_init(const f16* mp, float& floorm) {
  float mn = 3.4e38f;
  #pragma unroll
  for (int tq = 0; tq < 20; ++tq) mn = fminf(mn, (float)mp[tq * NFP]);
  const float initm = fmaxf(mn, 1e-5f);
  floorm = 0.5f * initm;
  return initm;
}

static __device__ __forceinline__ float k2_advance(const f16* rp, int n, float nf,
                                                   float rise, float fall, float floorm) {
  int t = 0;
  for (; t + 16 <= n; t += 16) {
    float m[16];
    #pragma unroll
    for (int q = 0; q < 16; ++q) m[q] = (float)rp[(size_t)(t + q) * NFP];
    #pragma unroll
    for (int q = 0; q < 16; ++q) {
      float a = (m[q] > nf) ? rise : fall;
      nf = fmaxf(fmaf(a, m[q] - nf, nf), floorm);
    }
  }
  for (; t < n; ++t) {
    float m = (float)rp[(size_t)t * NFP];
    float a = (m > nf) ? rise : fall;
    nf = fmaxf(fmaf(a, m - nf, nf), floorm);
  }
  return nf;
}

static __device__ __forceinline__ void k2_payload(const f16* src, f16* dst, int n,
                                                  float nf, float rise, float fall,
                                                  float floorm, float scale) {
  int t = 0;
  for (; t + 16 <= n; t += 16) {
    float m[16];
    #pragma unroll
    for (int q = 0; q < 16; ++q) m[q] = (float)src[(size_t)(t + q) * NFP];
    #pragma unroll
    for (int q = 0; q < 16; ++q) {
      float a = (m[q] > nf) ? rise : fall;
      nf = fmaxf(fmaf(a, m[q] - nf, nf), floorm);
      float v = m[q] / fmaf(scale, nf, 1e-8f);
      dst[(size_t)(t + q) * NFP] = (f16)fminf(v, 30000.f);
    }
  }
  for (; t < n; ++t) {
    float m = (float)src[(size_t)t * NFP];
    float a = (m > nf) ? rise : fall;
    nf = fmaxf(fmaf(a, m - nf, nf), floorm);
    float v = m / fmaf(scale, nf, 1e-8f);
    dst[(size_t)t * NFP] = (f16)fminf(v, 30000.f);
  }
}

// K2 fused (two-buffer path)
__global__ __launch_bounds__(256) void k2_fused(const f16* __restrict__ mv,
                                                f16* __restrict__ vnr,
                                                const float* __restrict__ nscp,
                                                const float* __restrict__ rrp,
                                                const float* __restrict__ rfp) {
  const int gid   = blockIdx.x * 256 + threadIdx.x;
  const int chunk = gid / NCHAN;
  const int ch    = gid - chunk * NCHAN;
  const int b     = ch / NF;
  const int f     = ch - b * NF;

  const float rise  = sigmoidf_(rrp[0]);
  const float fall  = sigmoidf_(rfp[0]);
  const float scale = fabsf(nscp[0]);

  const size_t cb = (size_t)b * TFRM * NFP + f;
  const f16* mp = mv + cb;

  float floorm;
  float nf = k2_init(mp, floorm);

  const int t0 = chunk * CT;
  const int t1 = (t0 + CT < TFRM) ? (t0 + CT) : TFRM;
  const int ts = (t0 > WARM) ? (t0 - WARM) : 0;

  nf = k2_advance(mp + (size_t)ts * NFP, t0 - ts, nf, rise, fall, floorm);
  k2_payload(mp + (size_t)t0 * NFP, vnr + cb + (size_t)t0 * NFP, t1 - t0,
             nf, rise, fall, floorm, scale);
}

// K2a (in-place path)
__global__ __launch_bounds__(256) void k2_warm(const f16* __restrict__ mv,
                                               float2* __restrict__ state,
                                               const float* __restrict__ rrp,
                                               const float* __restrict__ rfp) {
  const int gid   = blockIdx.x * 256 + threadIdx.x;
  const int chunk = gid / NCHAN;
  const int ch    = gid - chunk * NCHAN;
  const int b     = ch / NF;
  const int f     = ch - b * NF;

  const float rise = sigmoidf_(rrp[0]);
  const float fall = sigmoidf_(rfp[0]);

  const f16* mp = mv + (size_t)b * TFRM * NFP + f;
  float floorm;
  float nf = k2_init(mp, floorm);

  const int t0 = chunk * CT;
  const int ts = (t0 > WARM) ? (t0 - WARM) : 0;
  nf = k2_advance(mp + (size_t)ts * NFP, t0 - ts, nf, rise, fall, floorm);
  state[gid] = make_float2(nf, floorm);
}

// K2b (in-place path)
__global__ __launch_bounds__(256) void k2_main(f16* __restrict__ mv,
                                               const float2* __restrict__ state,
                                               const float* __restrict__ nscp,
                                               const float* __restrict__ rrp,
                                               const float* __restrict__ rfp) {
  const int gid   = blockIdx.x * 256 + threadIdx.x;
  const int chunk = gid / NCHAN;
  const int ch    = gid - chunk * NCHAN;
  const int b     = ch / NF;
  const int f     = ch - b * NF;

  const float rise  = sigmoidf_(rrp[0]);
  const float fall  = sigmoidf_(rfp[0]);
  const float scale = fabsf(nscp[0]);

  const float2 st = state[gid];
  const int t0 = chunk * CT;
  const int t1 = (t0 + CT < TFRM) ? (t0 + CT) : TFRM;

  f16* p = mv + (size_t)b * TFRM * NFP + f + (size_t)t0 * NFP;
  k2_payload(p, p, t1 - t0, st.x, rise, fall, st.y, scale);
}

// ---------------------------------------------------------------------------
// K3: ordered band sweep, one thread per (b,t) row, NO LDS data staging.
// Row read straight from global as 129 aligned uint loads (2 halfs each;
// NFP=258 stride makes every row 4B-aligned). Band-advance control depends
// only on f -> uniform across lanes. Stores coalesced (consecutive t).
// MODE 0: dst = fb@mv ; MODE 1: dst = tanh(fb@mv/10)
// ---------------------------------------------------------------------------
template<int MODE>
__global__ __launch_bounds__(256) void k3_sweep(const f16* __restrict__ mv,
                                                const float4* __restrict__ pf,
                                                float* __restrict__ dst) {
  __shared__ float4 pfl[NFP];

  const int tid = threadIdx.x;
  for (int i = tid; i < NFP; i += 256) pfl[i] = pf[i];
  __syncthreads();

  const int gid = blockIdx.x * 256 + tid;
  if (gid >= NBATCH * TFRM) return;
  const int b = gid / TFRM;
  const int t = gid - b * TFRM;

  const uint* rowp = (const uint*)(mv + ((size_t)b * TFRM + t) * NFP);
  float* op = dst + (size_t)b * NB * TFRM + t;       // + n*TFRM per band

  float accA = 0.f, accB = 0.f;
  int cur = -2, nw = 0;

#define K3_STORE(n_, v_) do { \
    float vv = (v_); if (MODE == 1) vv = tanhf(vv * 0.1f); \
    op[(size_t)(n_) * TFRM] = vv; } while (0)
#define K3_EMIT(n_, v_) do { int nn = (n_); \
    while (nw < nn && nw < NB) { op[(size_t)nw * TFRM] = 0.f; ++nw; } \
    if (nn < NB) { K3_STORE(nn, v_); nw = nn + 1; } } while (0)
#define K3_PROC(ff_, mm_) do { \
    float4 w = pfl[ff_]; \
    if (w.y != 0.f) { \
      const int n0 = __float_as_int(w.x); \
      if (n0 != cur) { \
        if (cur >= 0) { \
          if (n0 == cur + 1) { K3_EMIT(cur, accA); accA = accB; accB = 0.f; } \
          else { K3_EMIT(cur, accA); K3_EMIT(cur + 1, accB); accA = 0.f; accB = 0.f; } \
        } \
        cur = n0; \
      } \
      accA = fmaf(w.y, (mm_), accA); \
      accB = fmaf(w.w, (mm_), accB); \
    } } while (0)

  #pragma unroll 4
  for (int jp = 0; jp < NFP / 2; ++jp) {
    const uint u = rowp[jp];
    const f16x2 h = __builtin_bit_cast(f16x2, u);
    K3_PROC(2 * jp,     (float)h.x);
    K3_PROC(2 * jp + 1, (float)h.y);
  }
  if (cur >= 0) { K3_EMIT(cur, accA); K3_EMIT(cur + 1, accB); }
  while (nw < NB) { op[(size_t)nw * TFRM] = 0.f; ++nw; }
#undef K3_PROC
#undef K3_EMIT
#undef K3_STORE
}

// ---------------------------------------------------------------------------
// K4: kurtosis gate + per-row standardize. Block per (b,band).
// ---------------------------------------------------------------------------
__device__ __forceinline__ float blk_sum(float v, float* scr) {
  #pragma unroll
  for (int o = 32; o > 0; o >>= 1) v += __shfl_down(v, o, 64);
  const int lane = threadIdx.x & 63, w = threadIdx.x >> 6;
  __syncthreads();
  if (lane == 0) scr[w] = v;
  __syncthreads();
  return scr[0] + scr[1] + scr[2] + scr[3];
}

__global__ __launch_bounds__(256) void k4_gate(const float* band,
                                               const float* vnrb,
                                               const float* gw,
                                               const float* gb,
                                               const float* gf,
                                               float* feat) {
  __shared__ float scr[4];
  const int bid = blockIdx.x;
  const int b = bid / NB, n = bid - b * NB;
  const size_t base = (size_t)(b * NB + n) * TFRM;
  const float* row = band + base;
  const float* vr  = vnrb + base;
  const int tid = threadIdx.x;

  float xl[16];
  float s1 = 0.f;
  #pragma unroll
  for (int q = 0; q < 16; ++q) {
    int i = tid + q * 256;
    xl[q] = (i < TFRM) ? row[i] : 0.f;
    s1 += xl[q];
  }
  s1 = blk_sum(s1, scr);
  const float mu = s1 * (1.f / 4001.f);

  float s2 = 0.f, s4 = 0.f;
  #pragma unroll
  for (int q = 0; q < 16; ++q) {
    int i = tid + q * 256;
    if (i < TFRM) { float d = xl[q] - mu; float d2 = d * d; s2 += d2; s4 += d2 * d2; }
  }
  s2 = blk_sum(s2, scr);
  s4 = blk_sum(s4, scr);
  const float var  = fmaxf(s2 * (1.f / 4001.f), 1e-8f);
  const float kurt = (s4 * (1.f / 4001.f)) / (var * var + 1e-8f);
  const float kn   = (kurt - 3.f) * (1.f / 3.f);

  const float fl = sigmoidf_(gf[n]);
  float g0 = sigmoidf_(fmaf(gw[n], kn, gb[n]));
  g0 = g0 * (1.f - fl) + fl;

  float sy = 0.f;
  #pragma unroll
  for (int q = 0; q < 16; ++q) {
    int i = tid + q * 256;
    if (i < TFRM) {
      float y = xl[q] * g0 * (0.5f + 0.5f * vr[i]);
      xl[q] = y; sy += y;
    } else xl[q] = 0.f;
  }
  sy = blk_sum(sy, scr);
  const float mean = sy * (1.f / 4001.f);

  float sv = 0.f;
  #pragma unroll
  for (int q = 0; q < 16; ++q) {
    int i = tid + q * 256;
    if (i < TFRM) { float d = xl[q] - mean; sv += d * d; }
  }
  sv = blk_sum(sv, scr);
  const float rstd = 1.f / sqrtf(sv * (1.f / 4001.f) + 1e-5f);

  #pragma unroll
  for (int q = 0; q < 16; ++q) {
    int i = tid + q * 256;
    if (i < TFRM) feat[base + i] = (xl[q] - mean) * rstd;
  }
}

// ---------------------------------------------------------------------------
extern "C" void kernel_launch(void* const* d_in, const int* in_sizes, int n_in,
                              void* d_out, int out_size, void* d_ws, size_t ws_size,
                              hipStream_t stream) {
  const float* vib = (const float*)d_in[0];
  const float* fb  = (const float*)d_in[1];
  const float* win = (const float*)d_in[2];
  const float* nsc = (const float*)d_in[3];
  const float* rr  = (const float*)d_in[4];
  const float* rf  = (const float*)d_in[5];
  const float* gw  = (const float*)d_in[6];
  const float* gb  = (const float*)d_in[7];
  const float* gf  = (const float*)d_in[8];
  float* out = (float*)d_out;
  (void)in_sizes; (void)n_in; (void)out_size;

  if (ws_size < IN_PLACE_NEED) return;   // diagnostic clean-fail

  f16*    mv   = (f16*)d_ws;
  float4* pf   = (float4*)((char*)d_ws + MV_BYTES);
  f16*    vnr2 = (f16*)((char*)d_ws + MV_BYTES + PF_BYTES);
  float2* state = (float2*)(out + OFFOUT);   // in-place path: parked in vnrb
                                             // region, consumed before k3<1>
  const bool twobuf = (ws_size >= TWO_BUF_NEED);

  const int k3blocks = (NBATCH * TFRM + 255) / 256;   // 501

  hipLaunchKernelGGL(k0_pf,   dim3(1),       dim3(512), 0, stream, fb, pf);
  hipLaunchKernelGGL(k1_stft, dim3(32, 251), dim3(256), 0, stream, vib, win, mv);

  if (twobuf) {
    hipLaunchKernelGGL(k2_fused,    dim3(514),      dim3(256), 0, stream, mv, vnr2, nsc, rr, rf);
    hipLaunchKernelGGL(k3_sweep<0>, dim3(k3blocks), dim3(256), 0, stream, mv,   pf, out);
    hipLaunchKernelGGL(k3_sweep<1>, dim3(k3blocks), dim3(256), 0, stream, vnr2, pf, out + OFFOUT);
  } else {
    hipLaunchKernelGGL(k2_warm,     dim3(514),      dim3(256), 0, stream, mv, state, rr, rf);
    hipLaunchKernelGGL(k3_sweep<0>, dim3(k3blocks), dim3(256), 0, stream, mv, pf, out);
    hipLaunchKernelGGL(k2_main,     dim3(514),      dim3(256), 0, stream, mv, state, nsc, rr, rf);
    hipLaunchKernelGGL(k3_sweep<1>, dim3(k3blocks), dim3(256), 0, stream, mv, pf, out + OFFOUT);
  }

  hipLaunchKernelGGL(k4_gate, dim3(1280), dim3(256), 0, stream,
                     out, out + OFFOUT, gw, gb, gf, out);
}

// Round 7
// 377.311 us; speedup vs baseline: 2.5134x; 1.2679x over previous
//
#include <hip/hip_runtime.h>
#include <math.h>
#include <cstddef>

#define T_SAMP 256000
#define TFRM   4001
#define NF     257
#define NFP    258            // padded row stride (516 B -> every row 4B-aligned)
#define NB     40
#define NBATCH 32
#define OFFOUT ((size_t)NBATCH*NB*TFRM)
#define TWO_PI 6.283185307179586f

typedef _Float16 f16;
typedef _Float16 f16x2 __attribute__((ext_vector_type(2)));

#define MV_ELEMS  ((size_t)NBATCH * TFRM * NFP)           // 33,032,256 halfs
#define MV_BYTES  (MV_ELEMS * 2)                          // 66,064,512
#define PF_BYTES  ((size_t)16384)
#define IN_PLACE_NEED (MV_BYTES + PF_BYTES)               // 66,080,896 <= proven 66,334,784
#define TWO_BUF_NEED  (2*MV_BYTES + PF_BYTES)

// K2 chunking
#define CHUNKS 16
#define CT     251            // ceil(4001/16)
#define WARM   288            // 0.9526^288 ~ 9e-7 (< fp16 noise)
#define NCHAN  (NBATCH * NF)  // 8224

static __device__ __forceinline__ float sigmoidf_(float x) { return 1.f/(1.f+expf(-x)); }

// ---------------- complex helpers + radix-4 FFT16 (W = e^{-2pi i/16}) -------
static __device__ __forceinline__ float2 cadd(float2 a, float2 b){return make_float2(a.x+b.x,a.y+b.y);}
static __device__ __forceinline__ float2 csub(float2 a, float2 b){return make_float2(a.x-b.x,a.y-b.y);}
static __device__ __forceinline__ float2 cmulc(float2 a, float cr, float ci){
  return make_float2(fmaf(a.x,cr,-a.y*ci), fmaf(a.x,ci, a.y*cr));}
static __device__ __forceinline__ float2 mulmi(float2 a){ return make_float2(a.y, -a.x); } // a * (-i)

static __device__ __forceinline__ void dft4(float2 t0,float2 t1,float2 t2,float2 t3,
                                            float2&y0,float2&y1,float2&y2,float2&y3){
  float2 A=cadd(t0,t2), B=csub(t0,t2), C=cadd(t1,t3), D=csub(t1,t3);
  y0=cadd(A,C); y2=csub(A,C);
  float2 mD=mulmi(D);
  y1=cadd(B,mD); y3=csub(B,mD);
}

static __device__ __forceinline__ void fft16(const float2* in, float2* out){
  float2 V[4][4];
  #pragma unroll
  for(int n0=0;n0<4;++n0)
    dft4(in[n0],in[n0+4],in[n0+8],in[n0+12],V[n0][0],V[n0][1],V[n0][2],V[n0][3]);
  const float C1=0.92387953251f, S1=0.38268343236f, R=0.70710678119f;
  V[1][1]=cmulc(V[1][1],  C1,-S1);
  V[1][2]=cmulc(V[1][2],   R,-R );
  V[1][3]=cmulc(V[1][3],  S1,-C1);
  V[2][1]=cmulc(V[2][1],   R,-R );
  V[2][2]=mulmi(V[2][2]);               // W16^4 = -i
  V[2][3]=cmulc(V[2][3],  -R,-R );
  V[3][1]=cmulc(V[3][1],  S1,-C1);
  V[3][2]=cmulc(V[3][2],  -R,-R );
  V[3][3]=cmulc(V[3][3], -C1, S1);      // W16^9 = -W16^1
  #pragma unroll
  for(int q=0;q<4;++q)
    dft4(V[0][q],V[1][q],V[2][q],V[3][q],out[q],out[q+4],out[q+8],out[q+12]);
}

// ---------------------------------------------------------------------------
// K0: per-frequency band table, NFP entries; entry 257 (pad) zeroed.
// ---------------------------------------------------------------------------
__global__ __launch_bounds__(512) void k0_pf(const float* __restrict__ fb,
                                             float4* __restrict__ pf) {
  const int f = threadIdx.x;
  if (f >= NFP) return;
  if (f == NFP - 1) { pf[f] = make_float4(0.f, 0.f, 0.f, 0.f); return; }
  int n0 = 0, n1 = 0; float w0 = 0.f, w1 = 0.f;
  #pragma unroll 8
  for (int n = 0; n < NB; ++n) {
    float v = fb[n * NF + f];
    if (v > 0.f) { if (w0 == 0.f) { n0 = n; w0 = v; } else { n1 = n; w1 = v; } }
  }
  float4 o;
  o.x = __int_as_float(n0); o.y = w0;
  o.z = __int_as_float(n1); o.w = w1;
  pf[f] = o;
}

// ---------------------------------------------------------------------------
// K1: STFT magnitude -> fp16 mv[b][t][NFP]. 16 frames/block, 16 thr/frame.
// ---------------------------------------------------------------------------
__global__ __launch_bounds__(256) void k1_stft(const float* __restrict__ vib,
                                               const float* __restrict__ window,
                                               f16* __restrict__ mv) {
  __shared__ float4 xs4[368];            // 1472 floats input span
  __shared__ float2 win2[256];
  __shared__ float2 w256[256];
  __shared__ float  w512c[257];
  __shared__ float  w512s[257];
  __shared__ float2 Hst[16][16][16];     // [frame][c][r^c]; aliased as Z after
  __shared__ f16    lmag[16 * NFP];      // padded rows

  float*  xsf = (float*)xs4;
  float2 (*Zb)[256] = (float2(*)[256])Hst;

  const int tid = threadIdx.x;
  const int b   = blockIdx.x;
  const int t0  = blockIdx.y * 16;

  {
    win2[tid] = ((const float2*)window)[tid];
    float sv, cv;
    sincosf(TWO_PI * (float)tid * (1.f/256.f), &sv, &cv);
    w256[tid] = make_float2(cv, -sv);
    for (int i = tid; i < 257; i += 256) {
      float s3, c3;
      sincosf(TWO_PI * (float)i * (1.f/512.f), &s3, &c3);
      w512c[i] = c3; w512s[i] = s3;
    }
  }

  const int s0 = t0 * 64 - 256;
  for (int i = tid; i < 1472; i += 256) {
    int m = s0 + i;
    m = (m < 0) ? -m : m;
    if (m >= T_SAMP) m = 2*(T_SAMP-1) - m;
    xsf[i] = vib[(size_t)b * T_SAMP + m];
  }
  __syncthreads();

  const int fl = tid >> 4;
  const int r  = tid & 15;
  const int t  = t0 + fl;

  float2 z[16];
  const float2* xz = (const float2*)(xsf + fl * 64);
  #pragma unroll
  for (int a = 0; a < 16; ++a) {
    float2 xv = xz[r + 16*a];
    float2 wv = win2[r + 16*a];
    z[a] = make_float2(xv.x * wv.x, xv.y * wv.y);
  }

  // stage A: G = FFT16(z); twiddle; store
  float2 G[16];
  fft16(z, G);
  #pragma unroll
  for (int c = 0; c < 16; ++c) {
    float2 tw = w256[(r*c) & 255];
    float2 h;
    h.x = G[c].x*tw.x - G[c].y*tw.y;
    h.y = G[c].x*tw.y + G[c].y*tw.x;
    Hst[fl][c][r ^ c] = h;
  }
  __syncthreads();

  // stage B
  float2 hv[16];
  #pragma unroll
  for (int q = 0; q < 16; ++q) hv[q] = Hst[fl][r][q ^ r];
  __syncthreads();
  float2 Zv[16];
  fft16(hv, Zv);
  #pragma unroll
  for (int d = 0; d < 16; ++d) Zb[fl][r + 16*d] = Zv[d];
  __syncthreads();

  // stage C: rfft untangle + |X| -> LDS (fp16)
  if (t < TFRM) {
    #pragma unroll
    for (int j = 0; j < 17; ++j) {
      int k = r + 16*j;
      if (j == 16) { if (r != 0) break; k = 256; }
      float2 A  = Zb[fl][k & 255];
      float2 Bv = Zb[fl][(256 - k) & 255];
      float Er = 0.5f*(A.x + Bv.x), Ei = 0.5f*(A.y - Bv.y);
      float Dr = 0.5f*(A.x - Bv.x), Di = 0.5f*(A.y + Bv.y);
      float tc = w512c[k], ts = w512s[k];
      float Xr = Er + tc*Di - ts*Dr;
      float Xi = Ei - tc*Dr - ts*Di;
      lmag[fl * NFP + k] = (f16)sqrtf(Xr*Xr + Xi*Xi);
    }
  }
  __syncthreads();

  // linear coalesced copy-out (uint; both src and dst rows 4B-aligned)
  const int nv = (TFRM - t0 < 16) ? (TFRM - t0) : 16;
  const uint* ls = (const uint*)lmag;
  uint* dst32 = (uint*)(mv + ((size_t)b * TFRM + t0) * NFP);
  const int n32 = nv * (NFP / 2);
  for (int i = tid; i < n32; i += 256) dst32[i] = ls[i];
}

// ---------------------------------------------------------------------------
// K2 inner helpers (stride NFP)
// ---------------------------------------------------------------------------
static __device__ __forceinline__ float k2_init(const f16* mp, float& floorm) {
  float mn = 3.4e38f;
  #pragma unroll
  for (int tq = 0; tq < 20; ++tq) mn = fminf(mn, (float)mp[tq * NFP]);
  const float initm = fmaxf(mn, 1e-5f);
  floorm = 0.5f * initm;
  return initm;
}

static __device__ __forceinline__ float k2_advance(const f16* rp, int n, float nf,
                                                   float rise, float fall, float floorm) {
  int t = 0;
  for (; t + 16 <= n; t += 16) {
    float m[16];
    #pragma unroll
    for (int q = 0; q < 16; ++q) m[q] = (float)rp[(size_t)(t + q) * NFP];
    #pragma unroll
    for (int q = 0; q < 16; ++q) {
      float a = (m[q] > nf) ? rise : fall;
      nf = fmaxf(fmaf(a, m[q] - nf, nf), floorm);
    }
  }
  for (; t < n; ++t) {
    float m = (float)rp[(size_t)t * NFP];
    float a = (m > nf) ? rise : fall;
    nf = fmaxf(fmaf(a, m - nf, nf), floorm);
  }
  return nf;
}

static __device__ __forceinline__ void k2_payload(const f16* src, f16* dst, int n,
                                                  float nf, float rise, float fall,
                                                  float floorm, float scale) {
  int t = 0;
  for (; t + 16 <= n; t += 16) {
    float m[16];
    #pragma unroll
    for (int q = 0; q < 16; ++q) m[q] = (float)src[(size_t)(t + q) * NFP];
    #pragma unroll
    for (int q = 0; q < 16; ++q) {
      float a = (m[q] > nf) ? rise : fall;
      nf = fmaxf(fmaf(a, m[q] - nf, nf), floorm);
      float v = m[q] / fmaf(scale, nf, 1e-8f);
      dst[(size_t)(t + q) * NFP] = (f16)fminf(v, 30000.f);
    }
  }
  for (; t < n; ++t) {
    float m = (float)src[(size_t)t * NFP];
    float a = (m > nf) ? rise : fall;
    nf = fmaxf(fmaf(a, m - nf, nf), floorm);
    float v = m / fmaf(scale, nf, 1e-8f);
    dst[(size_t)t * NFP] = (f16)fminf(v, 30000.f);
  }
}

// K2 fused (two-buffer path)
__global__ __launch_bounds__(256) void k2_fused(const f16* __restrict__ mv,
                                                f16* __restrict__ vnr,
                                                const float* __restrict__ nscp,
                                                const float* __restrict__ rrp,
                                                const float* __restrict__ rfp) {
  const int gid   = blockIdx.x * 256 + threadIdx.x;
  const int chunk = gid / NCHAN;
  const int ch    = gid - chunk * NCHAN;
  const int b     = ch / NF;
  const int f     = ch - b * NF;

  const float rise  = sigmoidf_(rrp[0]);
  const float fall  = sigmoidf_(rfp[0]);
  const float scale = fabsf(nscp[0]);

  const size_t cb = (size_t)b * TFRM * NFP + f;
  const f16* mp = mv + cb;

  float floorm;
  float nf = k2_init(mp, floorm);

  const int t0 = chunk * CT;
  const int t1 = (t0 + CT < TFRM) ? (t0 + CT) : TFRM;
  const int ts = (t0 > WARM) ? (t0 - WARM) : 0;

  nf = k2_advance(mp + (size_t)ts * NFP, t0 - ts, nf, rise, fall, floorm);
  k2_payload(mp + (size_t)t0 * NFP, vnr + cb + (size_t)t0 * NFP, t1 - t0,
             nf, rise, fall, floorm, scale);
}

// K2a (in-place path)
__global__ __launch_bounds__(256) void k2_warm(const f16* __restrict__ mv,
                                               float2* __restrict__ state,
                                               const float* __restrict__ rrp,
                                               const float* __restrict__ rfp) {
  const int gid   = blockIdx.x * 256 + threadIdx.x;
  const int chunk = gid / NCHAN;
  const int ch    = gid - chunk * NCHAN;
  const int b     = ch / NF;
  const int f     = ch - b * NF;

  const float rise = sigmoidf_(rrp[0]);
  const float fall = sigmoidf_(rfp[0]);

  const f16* mp = mv + (size_t)b * TFRM * NFP + f;
  float floorm;
  float nf = k2_init(mp, floorm);

  const int t0 = chunk * CT;
  const int ts = (t0 > WARM) ? (t0 - WARM) : 0;
  nf = k2_advance(mp + (size_t)ts * NFP, t0 - ts, nf, rise, fall, floorm);
  state[gid] = make_float2(nf, floorm);
}

// K2b (in-place path)
__global__ __launch_bounds__(256) void k2_main(f16* __restrict__ mv,
                                               const float2* __restrict__ state,
                                               const float* __restrict__ nscp,
                                               const float* __restrict__ rrp,
                                               const float* __restrict__ rfp) {
  const int gid   = blockIdx.x * 256 + threadIdx.x;
  const int chunk = gid / NCHAN;
  const int ch    = gid - chunk * NCHAN;
  const int b     = ch / NF;
  const int f     = ch - b * NF;

  const float rise  = sigmoidf_(rrp[0]);
  const float fall  = sigmoidf_(rfp[0]);
  const float scale = fabsf(nscp[0]);

  const float2 st = state[gid];
  const int t0 = chunk * CT;
  const int t1 = (t0 + CT < TFRM) ? (t0 + CT) : TFRM;

  f16* p = mv + (size_t)b * TFRM * NFP + f + (size_t)t0 * NFP;
  k2_payload(p, p, t1 - t0, st.x, rise, fall, st.y, scale);
}

// ---------------------------------------------------------------------------
// K3: ordered band sweep, one thread per (b,t) row, f-chunked LDS staging.
// Per chunk: stage 256 rows x 32 uints coalesced (wave = 2 rows x 128B),
// tile stride 33 -> <=2-way banks. Sweep carries (cur,nw,accA,accB) across
// chunks; control depends only on f (uniform). Stores coalesced along t.
// MODE 0: dst = fb@mv ; MODE 1: dst = tanh(fb@mv/10)
// ---------------------------------------------------------------------------
template<int MODE>
__global__ __launch_bounds__(256) void k3_sweep(const f16* __restrict__ mv,
                                                const float4* __restrict__ pf,
                                                float* __restrict__ dst) {
  __shared__ uint   tile[256][33];      // 33792 B
  __shared__ float4 pfl[NFP];           // 4128 B

  const int tid = threadIdx.x;
  const int b   = blockIdx.x;
  const int t0  = blockIdx.y * 256;

  for (int i = tid; i < NFP; i += 256) pfl[i] = pf[i];

  const uint* gbase = (const uint*)(mv + (size_t)b * TFRM * NFP);  // 129 uints/row
  const int t   = t0 + tid;
  const bool act = t < TFRM;
  float* op = dst + (size_t)b * NB * TFRM + t;       // + n*TFRM per band

  float accA = 0.f, accB = 0.f;
  int cur = -2, nw = 0;

#define K3_STORE(n_, v_) do { \
    float vv = (v_); if (MODE == 1) vv = tanhf(vv * 0.1f); \
    if (act) op[(size_t)(n_) * TFRM] = vv; } while (0)
#define K3_EMIT(n_, v_) do { int nn = (n_); \
    while (nw < nn && nw < NB) { if (act) op[(size_t)nw * TFRM] = 0.f; ++nw; } \
    if (nn < NB) { K3_STORE(nn, v_); nw = nn + 1; } } while (0)
#define K3_PROC(ff_, mm_) do { \
    float4 w = pfl[ff_]; \
    if (w.y != 0.f) { \
      const int n0 = __float_as_int(w.x); \
      if (n0 != cur) { \
        if (cur >= 0) { \
          if (n0 == cur + 1) { K3_EMIT(cur, accA); accA = accB; accB = 0.f; } \
          else { K3_EMIT(cur, accA); K3_EMIT(cur + 1, accB); accA = 0.f; accB = 0.f; } \
        } \
        cur = n0; \
      } \
      accA = fmaf(w.y, (mm_), accA); \
      accB = fmaf(w.w, (mm_), accB); \
    } } while (0)

  for (int chk = 0; chk < 5; ++chk) {
    const int cbase = chk * 32;                     // uint col base
    __syncthreads();                                // tile reusable
    if (chk < 4) {
      #pragma unroll
      for (int k = 0; k < 32; ++k) {
        const int lin = k * 256 + tid;
        const int r = lin >> 5, j = lin & 31;
        int tt = t0 + r; if (tt > TFRM - 1) tt = TFRM - 1;
        tile[r][j] = gbase[(size_t)tt * 129 + cbase + j];
      }
    } else {
      int tt = t; if (tt > TFRM - 1) tt = TFRM - 1;
      tile[tid][0] = gbase[(size_t)tt * 129 + 128]; // halfs 256 + pad
    }
    __syncthreads();
    const int ncol = (chk < 4) ? 32 : 1;
    #pragma unroll 8
    for (int j = 0; j < ncol; ++j) {
      const uint u = tile[tid][j];
      const f16x2 h = __builtin_bit_cast(f16x2, u);
      const int f = 2 * (cbase + j);
      K3_PROC(f,     (float)h.x);
      K3_PROC(f + 1, (float)h.y);                   // f=257: zeroed entry, skipped
    }
  }
  if (cur >= 0) { K3_EMIT(cur, accA); K3_EMIT(cur + 1, accB); }
  while (nw < NB) { if (act) op[(size_t)nw * TFRM] = 0.f; ++nw; }
#undef K3_PROC
#undef K3_EMIT
#undef K3_STORE
}

// ---------------------------------------------------------------------------
// K4: kurtosis gate + per-row standardize. Block per (b,band).
// ---------------------------------------------------------------------------
__device__ __forceinline__ float blk_sum(float v, float* scr) {
  #pragma unroll
  for (int o = 32; o > 0; o >>= 1) v += __shfl_down(v, o, 64);
  const int lane = threadIdx.x & 63, w = threadIdx.x >> 6;
  __syncthreads();
  if (lane == 0) scr[w] = v;
  __syncthreads();
  return scr[0] + scr[1] + scr[2] + scr[3];
}

__global__ __launch_bounds__(256) void k4_gate(const float* band,
                                               const float* vnrb,
                                               const float* gw,
                                               const float* gb,
                                               const float* gf,
                                               float* feat) {
  __shared__ float scr[4];
  const int bid = blockIdx.x;
  const int b = bid / NB, n = bid - b * NB;
  const size_t base = (size_t)(b * NB + n) * TFRM;
  const float* row = band + base;
  const float* vr  = vnrb + base;
  const int tid = threadIdx.x;

  float xl[16];
  float s1 = 0.f;
  #pragma unroll
  for (int q = 0; q < 16; ++q) {
    int i = tid + q * 256;
    xl[q] = (i < TFRM) ? row[i] : 0.f;
    s1 += xl[q];
  }
  s1 = blk_sum(s1, scr);
  const float mu = s1 * (1.f / 4001.f);

  float s2 = 0.f, s4 = 0.f;
  #pragma unroll
  for (int q = 0; q < 16; ++q) {
    int i = tid + q * 256;
    if (i < TFRM) { float d = xl[q] - mu; float d2 = d * d; s2 += d2; s4 += d2 * d2; }
  }
  s2 = blk_sum(s2, scr);
  s4 = blk_sum(s4, scr);
  const float var  = fmaxf(s2 * (1.f / 4001.f), 1e-8f);
  const float kurt = (s4 * (1.f / 4001.f)) / (var * var + 1e-8f);
  const float kn   = (kurt - 3.f) * (1.f / 3.f);

  const float fl = sigmoidf_(gf[n]);
  float g0 = sigmoidf_(fmaf(gw[n], kn, gb[n]));
  g0 = g0 * (1.f - fl) + fl;

  float sy = 0.f;
  #pragma unroll
  for (int q = 0; q < 16; ++q) {
    int i = tid + q * 256;
    if (i < TFRM) {
      float y = xl[q] * g0 * (0.5f + 0.5f * vr[i]);
      xl[q] = y; sy += y;
    } else xl[q] = 0.f;
  }
  sy = blk_sum(sy, scr);
  const float mean = sy * (1.f / 4001.f);

  float sv = 0.f;
  #pragma unroll
  for (int q = 0; q < 16; ++q) {
    int i = tid + q * 256;
    if (i < TFRM) { float d = xl[q] - mean; sv += d * d; }
  }
  sv = blk_sum(sv, scr);
  const float rstd = 1.f / sqrtf(sv * (1.f / 4001.f) + 1e-5f);

  #pragma unroll
  for (int q = 0; q < 16; ++q) {
    int i = tid + q * 256;
    if (i < TFRM) feat[base + i] = (xl[q] - mean) * rstd;
  }
}

// ---------------------------------------------------------------------------
extern "C" void kernel_launch(void* const* d_in, const int* in_sizes, int n_in,
                              void* d_out, int out_size, void* d_ws, size_t ws_size,
                              hipStream_t stream) {
  const float* vib = (const float*)d_in[0];
  const float* fb  = (const float*)d_in[1];
  const float* win = (const float*)d_in[2];
  const float* nsc = (const float*)d_in[3];
  const float* rr  = (const float*)d_in[4];
  const float* rf  = (const float*)d_in[5];
  const float* gw  = (const float*)d_in[6];
  const float* gb  = (const float*)d_in[7];
  const float* gf  = (const float*)d_in[8];
  float* out = (float*)d_out;
  (void)in_sizes; (void)n_in; (void)out_size;

  if (ws_size < IN_PLACE_NEED) return;   // diagnostic clean-fail

  f16*    mv   = (f16*)d_ws;
  float4* pf   = (float4*)((char*)d_ws + MV_BYTES);
  f16*    vnr2 = (f16*)((char*)d_ws + MV_BYTES + PF_BYTES);
  float2* state = (float2*)(out + OFFOUT);   // in-place path: parked in vnrb
                                             // region, consumed before k3<1>
  const bool twobuf = (ws_size >= TWO_BUF_NEED);

  const dim3 k3grid(32, (TFRM + 255) / 256);   // (32,16)

  hipLaunchKernelGGL(k0_pf,   dim3(1),       dim3(512), 0, stream, fb, pf);
  hipLaunchKernelGGL(k1_stft, dim3(32, 251), dim3(256), 0, stream, vib, win, mv);

  if (twobuf) {
    hipLaunchKernelGGL(k2_fused,    dim3(514), dim3(256), 0, stream, mv, vnr2, nsc, rr, rf);
    hipLaunchKernelGGL(k3_sweep<0>, k3grid,    dim3(256), 0, stream, mv,   pf, out);
    hipLaunchKernelGGL(k3_sweep<1>, k3grid,    dim3(256), 0, stream, vnr2, pf, out + OFFOUT);
  } else {
    hipLaunchKernelGGL(k2_warm,     dim3(514), dim3(256), 0, stream, mv, state, rr, rf);
    hipLaunchKernelGGL(k3_sweep<0>, k3grid,    dim3(256), 0, stream, mv, pf, out);
    hipLaunchKernelGGL(k2_main,     dim3(514), dim3(256), 0, stream, mv, state, nsc, rr, rf);
    hipLaunchKernelGGL(k3_sweep<1>, k3grid,    dim3(256), 0, stream, mv, pf, out + OFFOUT);
  }

  hipLaunchKernelGGL(k4_gate, dim3(1280), dim3(256), 0, stream,
                     out, out + OFFOUT, gw, gb, gf, out);
}